// Round 3
// baseline (233.645 us; speedup 1.0000x reference)
//
#include <hip/hip_runtime.h>

// IDWT reconstruction layer, LDS-staged via global_load_lds DMA.
// x: (B=16, L=32768, 64) f32, channels [0,32)=approx A, [32,64)=detail D.
// out: (16, 65536, 32) f32.
//
// out[b, 2p,   c] = sum_t lo[2t+1]*A[b,p-1+t,c] + hi[2t+1]*D[b,p-1+t,c]
// out[b, 2p+1, c] = sum_t lo[2t  ]*A[b,p-1+t,c] + hi[2t  ]*D[b,p-1+t,c]
//
// Block = 256 threads handles TP=128 consecutive p rows of one batch.
// Stage rows p0-1 .. p0+130 (132 rows x 256 B = 33 KB) into LDS with
// dense 1 KB-per-wave-instruction async DMA (deep outstanding-request
// queue -> breaks the ~30-line/CU miss-concurrency cap seen in R2).
// Edge tiles (pt==0 / pt==255) use a clamped manual staging path.

#define B_    16
#define L_    32768
#define CIN_  64
#define COUT_ 32
#define TP    128
#define ROWS  (TP + 4)            // 132 staged rows (131 used + 1 DMA spare)
#define NCHUNK ((ROWS * CIN_ * 4) / 1024)   // 33 chunks of 1024 B

typedef float vf4 __attribute__((ext_vector_type(4)));
typedef __attribute__((address_space(1))) const void gvoid_t;
typedef __attribute__((address_space(3))) void lvoid_t;

__global__ __launch_bounds__(256) void idwt_kernel(
    const float* __restrict__ x,
    const float* __restrict__ rec_lo,
    const float* __restrict__ rec_hi,
    float* __restrict__ out)
{
    __shared__ float slab[ROWS * CIN_];   // 33,792 B

    const int t   = threadIdx.x;
    const int blk = blockIdx.x;
    const int pt  = blk & 255;            // 32768/128 = 256 tiles per batch
    const int b   = blk >> 8;
    const int p0  = pt * TP;

    const float* batch = x + (size_t)b * (L_ * CIN_);

    if (pt != 0 && pt != 255) {
        // Fast path: rows p0-1 .. p0+130 all in-bounds within the batch.
        const float* src = batch + (size_t)(p0 - 1) * CIN_;
        const int w    = t >> 6;          // wave id 0..3
        const int lane = t & 63;
        for (int c = w; c < NCHUNK; c += 4) {
            const float* gp = src + c * 256 + lane * 4;   // dense 1 KB chunk
            __builtin_amdgcn_global_load_lds((gvoid_t*)gp,
                                             (lvoid_t*)&slab[c * 256],
                                             16, 0, 0);
        }
    } else {
        // Edge path: clamp + zero-fill, plain loads + ds_write.
        for (int idx = t; idx < ROWS * 16; idx += 256) {
            const int row = idx >> 4;     // staged row
            const int cg  = idx & 15;     // 16 B chunk within 256 B row
            const int j   = p0 - 1 + row;
            vf4 v = {0.f, 0.f, 0.f, 0.f};
            if (j >= 0 && j < L_)
                v = *(const vf4*)(batch + (size_t)j * CIN_ + cg * 4);
            *(vf4*)&slab[row * CIN_ + cg * 4] = v;
        }
    }

    // Wave-uniform filter loads (scalarized), issued before the barrier.
    float lo[8], hi[8];
#pragma unroll
    for (int k = 0; k < 8; ++k) { lo[k] = rec_lo[k]; hi[k] = rec_hi[k]; }

    __syncthreads();   // drains DMA (vmcnt) and ds_writes (lgkmcnt)

    // Compute: thread = channel group g (4 ch) x 4 consecutive p values.
    const int g  = t & 7;
    const int k4 = (t >> 3) * 4;          // p_local base: 0,4,...,124

    // Rolling 7-row window: lrow = k4 .. k4+6  (lrow = p_local + tap,
    // slab lrow holds global row p0-1+lrow).
    float A[7][4], D[7][4];
#pragma unroll
    for (int r = 0; r < 7; ++r) {
        const vf4 a = *(const vf4*)&slab[(k4 + r) * CIN_ + g * 4];
        const vf4 d = *(const vf4*)&slab[(k4 + r) * CIN_ + COUT_ + g * 4];
#pragma unroll
        for (int c = 0; c < 4; ++c) { A[r][c] = a[c]; D[r][c] = d[c]; }
    }

    float* orow = out + ((size_t)b * (2 * L_) + 2 * (p0 + k4)) * COUT_ + g * 4;
#pragma unroll
    for (int k = 0; k < 4; ++k) {
        vf4 ev, od;
#pragma unroll
        for (int c = 0; c < 4; ++c) {
            float e = 0.f, o = 0.f;
#pragma unroll
            for (int tap = 0; tap < 4; ++tap) {
                e = fmaf(lo[2 * tap + 1], A[k + tap][c], e);
                e = fmaf(hi[2 * tap + 1], D[k + tap][c], e);
                o = fmaf(lo[2 * tap],     A[k + tap][c], o);
                o = fmaf(hi[2 * tap],     D[k + tap][c], o);
            }
            ev[c] = e; od[c] = o;
        }
        __builtin_nontemporal_store(ev, (vf4*)(orow + (2 * k) * COUT_));
        __builtin_nontemporal_store(od, (vf4*)(orow + (2 * k + 1) * COUT_));
    }
}

extern "C" void kernel_launch(void* const* d_in, const int* in_sizes, int n_in,
                              void* d_out, int out_size, void* d_ws, size_t ws_size,
                              hipStream_t stream) {
    const float* x      = (const float*)d_in[0];
    const float* rec_lo = (const float*)d_in[1];
    const float* rec_hi = (const float*)d_in[2];
    float* out = (float*)d_out;

    const int nblocks = B_ * (L_ / TP);   // 16 * 256 = 4096
    idwt_kernel<<<nblocks, 256, 0, stream>>>(x, rec_lo, rec_hi, out);
}